// Round 1
// baseline (221.833 us; speedup 1.0000x reference)
//
#include <hip/hip_runtime.h>
#include <math.h>

#define H 16
#define L 4096
#define D 64
#define R 128
#define CHUNK 128
#define NC 32              // L / CHUNK
#define HL (H * L)
#define EPS 1e-10f
#define XS_SCALE 0.125f                    // sqrt(0.125) / 64^0.25 == 1/8 exactly
#define PHI_SCALE 0.08838834764831845f     // 1 / sqrt(128)

// ---------------------------------------------------------------- K1: phi ---
// One block handles 64 consecutive (h,l) rows. W (32KB) staged in LDS.
__global__ __launch_bounds__(256) void phi_kernel(const float* __restrict__ x,
                                                  const float* __restrict__ W,
                                                  float* __restrict__ phi) {
    __shared__ float W_lds[D * R];     // 32 KB
    __shared__ float xs_lds[64 * D];   // 16 KB
    __shared__ float sq_lds[64];
    const int tid = threadIdx.x;
    const int row0 = blockIdx.x * 64;  // flat (h*L + l) row

    for (int i = tid; i < D * R; i += 256) W_lds[i] = W[i];
    for (int i = tid; i < 64 * D; i += 256) xs_lds[i] = x[(size_t)row0 * D + i] * XS_SCALE;
    __syncthreads();
    if (tid < 64) {
        float s = 0.f;
        #pragma unroll
        for (int d = 0; d < D; ++d) { float t = xs_lds[tid * D + d]; s += t * t; }
        sq_lds[tid] = 0.5f * s;
    }
    __syncthreads();
    const int r = tid & 127;
    const int rb = tid >> 7;           // 0 or 1
    for (int rr = rb; rr < 64; rr += 2) {
        float acc = 0.f;
        #pragma unroll
        for (int d = 0; d < D; ++d) acc = fmaf(xs_lds[rr * D + d], W_lds[d * R + r], acc);
        phi[(size_t)(row0 + rr) * R + r] = __expf(acc - sq_lds[rr]) * PHI_SCALE;
    }
}

// ---------------------------------------------------- K2: per-chunk skv/zk ---
// skv[hn][r][d] = sum_c pk[hn][c][r] * v[hn][c][d];  zk[hn][r] = sum_c pk.
// skv is written into the d_out region (same chunk geometry: 128x64 floats).
__global__ __launch_bounds__(256) void skv_kernel(const float* __restrict__ pk,
                                                  const float* __restrict__ v,
                                                  float* __restrict__ skv,
                                                  float* __restrict__ zk) {
    __shared__ float pk_lds[CHUNK * R];  // 64 KB [c][r]
    __shared__ float v_lds[CHUNK * D];   // 32 KB [c][d]
    const int tid = threadIdx.x;
    const int hn = blockIdx.x;
    const float* pkc = pk + (size_t)hn * CHUNK * R;
    const float* vc  = v  + (size_t)hn * CHUNK * D;
    for (int i = tid; i < CHUNK * R; i += 256) pk_lds[i] = pkc[i];
    for (int i = tid; i < CHUNK * D; i += 256) v_lds[i]  = vc[i];
    __syncthreads();

    const int td = tid & 15, tr = tid >> 4;
    const int r0 = tr * 8, d0 = td * 4;
    float acc[8][4] = {};
    for (int c = 0; c < CHUNK; ++c) {
        float pkv[8], vv[4];
        #pragma unroll
        for (int i = 0; i < 8; ++i) pkv[i] = pk_lds[c * R + r0 + i];
        #pragma unroll
        for (int j = 0; j < 4; ++j) vv[j] = v_lds[c * D + d0 + j];
        #pragma unroll
        for (int i = 0; i < 8; ++i)
            #pragma unroll
            for (int j = 0; j < 4; ++j)
                acc[i][j] = fmaf(pkv[i], vv[j], acc[i][j]);
    }
    float* skvc = skv + (size_t)hn * R * D;
    #pragma unroll
    for (int i = 0; i < 8; ++i)
        #pragma unroll
        for (int j = 0; j < 4; ++j)
            skvc[(r0 + i) * D + d0 + j] = acc[i][j];

    if (tid < R) {
        float s = 0.f;
        for (int c = 0; c < CHUNK; ++c) s += pk_lds[c * R + tid];
        zk[(size_t)hn * R + tid] = s;
    }
}

// -------------------------------------------------- K3: exclusive scans -----
__global__ __launch_bounds__(256) void scan_skv(float* __restrict__ skv) {
    int id = blockIdx.x * 256 + threadIdx.x;   // H*R*D = 131072 columns
    int h  = id >> 13;                         // / (R*D)
    int rd = id & 8191;
    float* p = skv + (size_t)h * NC * R * D + rd;
    float run = 0.f;
    for (int n = 0; n < NC; ++n) {
        float val = p[(size_t)n * R * D];
        p[(size_t)n * R * D] = run;
        run += val;
    }
}

__global__ __launch_bounds__(256) void scan_zk(float* __restrict__ zk) {
    int id = blockIdx.x * 256 + threadIdx.x;   // H*R = 2048 columns
    int h = id >> 7;
    int r = id & 127;
    float* p = zk + (size_t)h * NC * R + r;
    float run = 0.f;
    for (int n = 0; n < NC; ++n) {
        float val = p[n * R];
        p[n * R] = run;
        run += val;
    }
}

// ----------------------------------------- K4: A = mask(pq_c . pk_c^T) ------
// A aliases the pk region (pk chunk fully staged to LDS before overwrite).
__global__ __launch_bounds__(256) void a_kernel(const float* __restrict__ pq,
                                                const float* __restrict__ pk,
                                                float* __restrict__ A) {
    __shared__ float pq_lds[CHUNK * 129];  // padded, 66048 B
    __shared__ float pk_lds[CHUNK * R];    // XOR-swizzled, 65536 B
    const int tid = threadIdx.x;
    const int hn = blockIdx.x;
    const float* pqc = pq + (size_t)hn * CHUNK * R;
    const float* pkc = pk + (size_t)hn * CHUNK * R;
    for (int i = tid; i < CHUNK * R; i += 256) {
        int row = i >> 7, col = i & 127;
        pq_lds[row * 129 + col] = pqc[i];
        pk_lds[row * 128 + (col ^ ((row >> 2) & 31))] = pkc[i];
    }
    __syncthreads();

    const int ts = tid & 15, tl = tid >> 4;
    const int l0 = tl * 8, s0 = ts * 8;
    float a[8][8] = {};
    for (int r = 0; r < R; ++r) {
        float qa[8], ka[8];
        #pragma unroll
        for (int i = 0; i < 8; ++i) qa[i] = pq_lds[(l0 + i) * 129 + r];
        #pragma unroll
        for (int j = 0; j < 8; ++j) {
            int s = s0 + j;
            ka[j] = pk_lds[s * 128 + (r ^ ((s >> 2) & 31))];
        }
        #pragma unroll
        for (int i = 0; i < 8; ++i)
            #pragma unroll
            for (int j = 0; j < 8; ++j)
                a[i][j] = fmaf(qa[i], ka[j], a[i][j]);
    }
    float* Ac = A + (size_t)hn * CHUNK * CHUNK;
    #pragma unroll
    for (int i = 0; i < 8; ++i) {
        int l = l0 + i;
        #pragma unroll
        for (int j = 0; j < 8; ++j) {
            int s = s0 + j;
            Ac[l * CHUNK + s] = (s < l) ? a[i][j] : 0.f;
        }
    }
}

// ------------------- K5: out = ([A|pq].[v;skv]) / ([A|pq].[1;zk] + eps) -----
// skv lives in d_out; every skv read is staged to LDS before any out write.
__global__ __launch_bounds__(256) void out_kernel(const float* __restrict__ pq,
                                                  const float* __restrict__ A,
                                                  const float* __restrict__ v,
                                                  const float* __restrict__ skv,
                                                  const float* __restrict__ zk,
                                                  float* __restrict__ out) {
    __shared__ float G_lds[CHUNK * 65];   // 33280 B [l][kk]
    __shared__ float Hm_lds[64 * D];      // 16 KB   [kk][d]
    __shared__ float dv_lds[64];
    const int tid = threadIdx.x;
    const int hn = blockIdx.x;
    const int td = tid & 15, tl = tid >> 4;
    const int l0 = tl * 8, d0 = td * 4;
    float acc[8][4] = {};
    float den[8] = {};

    for (int kt = 0; kt < 4; ++kt) {
        __syncthreads();
        if (kt < 2) {
            const float* Ac = A + (size_t)hn * CHUNK * CHUNK + kt * 64;
            for (int i = tid; i < CHUNK * 64; i += 256) {
                int row = i >> 6, col = i & 63;
                G_lds[row * 65 + col] = Ac[row * CHUNK + col];
            }
            const float* vc = v + (size_t)hn * CHUNK * D + kt * 64 * D;
            for (int i = tid; i < 64 * D; i += 256) Hm_lds[i] = vc[i];
            if (tid < 64) dv_lds[tid] = 1.0f;
        } else {
            const float* pqc = pq + (size_t)hn * CHUNK * R + (kt - 2) * 64;
            for (int i = tid; i < CHUNK * 64; i += 256) {
                int row = i >> 6, col = i & 63;
                G_lds[row * 65 + col] = pqc[row * R + col];
            }
            const float* skvc = skv + (size_t)hn * R * D + (kt - 2) * 64 * D;
            for (int i = tid; i < 64 * D; i += 256) Hm_lds[i] = skvc[i];
            if (tid < 64) dv_lds[tid] = zk[(size_t)hn * R + (kt - 2) * 64 + tid];
        }
        __syncthreads();
        for (int kk = 0; kk < 64; ++kk) {
            float g[8], hv[4];
            float dv = dv_lds[kk];
            #pragma unroll
            for (int i = 0; i < 8; ++i) g[i] = G_lds[(l0 + i) * 65 + kk];
            #pragma unroll
            for (int j = 0; j < 4; ++j) hv[j] = Hm_lds[kk * D + d0 + j];
            #pragma unroll
            for (int i = 0; i < 8; ++i) {
                den[i] = fmaf(g[i], dv, den[i]);
                #pragma unroll
                for (int j = 0; j < 4; ++j)
                    acc[i][j] = fmaf(g[i], hv[j], acc[i][j]);
            }
        }
    }
    float* oc = out + (size_t)hn * CHUNK * D;
    #pragma unroll
    for (int i = 0; i < 8; ++i) {
        float inv = 1.0f / (den[i] + EPS);
        #pragma unroll
        for (int j = 0; j < 4; ++j)
            oc[(l0 + i) * D + d0 + j] = acc[i][j] * inv;
    }
}

// ---------------------------------------------------------------------------
extern "C" void kernel_launch(void* const* d_in, const int* in_sizes, int n_in,
                              void* d_out, int out_size, void* d_ws, size_t ws_size,
                              hipStream_t stream) {
    // setup_inputs order: {T, k, q, v, W}
    const float* k = (const float*)d_in[1];
    const float* q = (const float*)d_in[2];
    const float* v = (const float*)d_in[3];
    const float* W = (const float*)d_in[4];
    float* out = (float*)d_out;

    // ws layout (floats): pq[H*L*R] | pk[H*L*R] | zk[H*NC*R]
    // total = (8388608*2 + 65536)*4 = 67,371,008 bytes (~64.3 MB)
    float* pq = (float*)d_ws;
    float* pk = pq + (size_t)H * L * R;
    float* zk = pk + (size_t)H * L * R;
    float* A  = pk;    // A overwrites pk region (safe: K4 stages pk chunk to LDS first)
    float* skv = out;  // skv lives in d_out (safe: K5 stages skv to LDS before writes)

    phi_kernel<<<HL / 64, 256, 0, stream>>>(q, W, pq);
    phi_kernel<<<HL / 64, 256, 0, stream>>>(k, W, pk);
    skv_kernel<<<H * NC, 256, 0, stream>>>(pk, v, skv, zk);
    a_kernel<<<H * NC, 256, 0, stream>>>(pq, pk, A);           // after skv (pk still intact there)
    scan_skv<<<(H * R * D) / 256, 256, 0, stream>>>(skv);
    scan_zk<<<(H * R) / 256, 256, 0, stream>>>(zk);
    out_kernel<<<H * NC, 256, 0, stream>>>(pq, A, v, skv, zk, out);
}

// Round 2
// 76.057 us; speedup vs baseline: 2.9167x; 2.9167x over previous
//
#include <hip/hip_runtime.h>

#define H 16
#define L 4096
#define D 64
#define R 128
#define CHUNK 128
#define NC 32
#define HL (H * L)
#define EPS 1e-10f
#define XS_SCALE 0.125f                    // sqrt(0.125)/64^0.25 == 1/8 exactly
#define PHI_SCALE 0.08838834764831845f     // 1/sqrt(128)

typedef __attribute__((ext_vector_type(8))) short bf8;     // 8 bf16 (4 VGPR)
typedef __attribute__((ext_vector_type(16))) float facc16; // 32x32 MFMA acc

__device__ __forceinline__ unsigned short f2b(float f) {
    unsigned u = __float_as_uint(f);
    return (unsigned short)((u + 0x7fffu + ((u >> 16) & 1u)) >> 16);  // RNE
}
__device__ __forceinline__ float b2f(unsigned short s) {
    return __uint_as_float(((unsigned)s) << 16);
}

// ---------------------------------------------------------------- K1: phi ---
// Block: 128 rows. phi = exp(xs.W - 0.5|xs|^2)/sqrt(R), bf16 out via MFMA.
// Wt[r][d] (transposed W) and xs[row][d] in LDS, XOR-swizzled, b128 frags.
__global__ __launch_bounds__(256) void phi_kernel(const float* __restrict__ x,
                                                  const float* __restrict__ W,
                                                  unsigned short* __restrict__ phi) {
    __shared__ __align__(16) unsigned short Wt[128 * 64];
    __shared__ __align__(16) unsigned short xs[128 * 64];
    __shared__ float sq[128];
    const int tid = threadIdx.x;
    const size_t row0 = (size_t)blockIdx.x * 128;

    for (int i = tid; i < 128 * 64; i += 256) {            // Wt[r][d] <- W[d][r]
        int r = i & 127, d = i >> 7;
        Wt[(unsigned)((r * 64 + d) ^ ((r & 7) << 3))] = f2b(W[d * 128 + r]);
    }
    for (int i = tid; i < 2048; i += 256) {                // xs + rowwise sq
        int row = i >> 4, d0 = (i & 15) * 4;
        const float4 vv = *(const float4*)(x + (row0 + row) * 64 + d0);
        float a0 = vv.x * XS_SCALE, a1 = vv.y * XS_SCALE;
        float a2 = vv.z * XS_SCALE, a3 = vv.w * XS_SCALE;
        float ss = a0 * a0 + a1 * a1 + a2 * a2 + a3 * a3;
        ss += __shfl_xor(ss, 1); ss += __shfl_xor(ss, 2);
        ss += __shfl_xor(ss, 4); ss += __shfl_xor(ss, 8);
        if ((tid & 15) == 0) sq[row] = 0.5f * ss;
        unsigned idx = (unsigned)((row * 64 + d0) ^ ((row & 7) << 3));
        unsigned* p = (unsigned*)&xs[idx];
        p[0] = (unsigned)f2b(a0) | ((unsigned)f2b(a1) << 16);
        p[1] = (unsigned)f2b(a2) | ((unsigned)f2b(a3) << 16);
    }
    __syncthreads();

    const int lane = tid & 63, wave = tid >> 6;
    const int lo = lane & 31, hi = lane >> 5;
    const int l0 = wave * 32;
    facc16 acc[4];
    #pragma unroll
    for (int t = 0; t < 4; ++t)
        #pragma unroll
        for (int e = 0; e < 16; ++e) acc[t][e] = 0.f;

    #pragma unroll
    for (int s = 0; s < 4; ++s) {                          // K = 64
        const bf8 a = *(const bf8*)&xs[(unsigned)(((l0 + lo) * 64 + 16 * s + 8 * hi) ^ (((l0 + lo) & 7) << 3))];
        #pragma unroll
        for (int t = 0; t < 4; ++t) {
            const bf8 b = *(const bf8*)&Wt[(unsigned)(((t * 32 + lo) * 64 + 16 * s + 8 * hi) ^ (((t * 32 + lo) & 7) << 3))];
            acc[t] = __builtin_amdgcn_mfma_f32_32x32x16_bf16(a, b, acc[t], 0, 0, 0);
        }
    }
    #pragma unroll
    for (int t = 0; t < 4; ++t)
        #pragma unroll
        for (int reg = 0; reg < 16; ++reg) {
            int row = l0 + (reg & 3) + 8 * (reg >> 2) + 4 * hi;
            int col = t * 32 + lo;
            float val = __expf(acc[t][reg] - sq[row]) * PHI_SCALE;
            phi[(row0 + row) * 128 + col] = f2b(val);
        }
}

// ---------------------------------------------- K2: per-chunk skv + zk ------
// skv[r][d] = sum_c pk[c][r] v[c][d]   (TN GEMM via u16-gather fragments)
__global__ __launch_bounds__(256) void skv_kernel(const unsigned short* __restrict__ pk,
                                                  const float* __restrict__ v,
                                                  float* __restrict__ skv,
                                                  float* __restrict__ zk) {
    __shared__ __align__(16) unsigned short pkl[128 * 128];  // [c][r] swz
    __shared__ __align__(16) unsigned short vl[128 * 64];    // [c][d] swz
    const int tid = threadIdx.x, hn = blockIdx.x;
    const unsigned short* pkg = pk + (size_t)hn * CHUNK * R;
    const float* vg = v + (size_t)hn * CHUNK * D;

    for (int i = tid; i < 2048; i += 256) {
        int c = i >> 4, rb = (i & 15) * 8;
        *(bf8*)&pkl[(unsigned)((c * 128 + rb) ^ ((c & 7) << 3))] = *(const bf8*)(pkg + c * 128 + rb);
    }
    for (int i = tid; i < 2048; i += 256) {
        int c = i >> 4, d0 = (i & 15) * 4;
        float4 vv = *(const float4*)(vg + c * 64 + d0);
        unsigned* p = (unsigned*)&vl[(unsigned)((c * 64 + d0) ^ ((c & 7) << 3))];
        p[0] = (unsigned)f2b(vv.x) | ((unsigned)f2b(vv.y) << 16);
        p[1] = (unsigned)f2b(vv.z) | ((unsigned)f2b(vv.w) << 16);
    }
    __syncthreads();

    if (tid < 128) {
        float s = 0.f;
        for (int c = 0; c < 128; ++c) s += b2f(pkl[(unsigned)((c * 128 + tid) ^ ((c & 7) << 3))]);
        zk[(size_t)hn * 128 + tid] = s;
    }

    const int lane = tid & 63, wave = tid >> 6, lo = lane & 31, hi = lane >> 5;
    const int r0 = wave * 32;
    facc16 acc[2];
    #pragma unroll
    for (int t = 0; t < 2; ++t)
        #pragma unroll
        for (int e = 0; e < 16; ++e) acc[t][e] = 0.f;

    #pragma unroll
    for (int s = 0; s < 8; ++s) {                          // K = 128 over c
        bf8 a;
        #pragma unroll
        for (int e = 0; e < 8; ++e) {
            int k = 16 * s + 8 * hi + e;
            a[e] = (short)pkl[(unsigned)((k * 128 + (r0 + lo)) ^ ((k & 7) << 3))];
        }
        #pragma unroll
        for (int t = 0; t < 2; ++t) {
            bf8 b;
            #pragma unroll
            for (int e = 0; e < 8; ++e) {
                int k = 16 * s + 8 * hi + e;
                b[e] = (short)vl[(unsigned)((k * 64 + (t * 32 + lo)) ^ ((k & 7) << 3))];
            }
            acc[t] = __builtin_amdgcn_mfma_f32_32x32x16_bf16(a, b, acc[t], 0, 0, 0);
        }
    }
    float* so = skv + (size_t)hn * R * D;
    #pragma unroll
    for (int t = 0; t < 2; ++t)
        #pragma unroll
        for (int reg = 0; reg < 16; ++reg) {
            int row = r0 + (reg & 3) + 8 * (reg >> 2) + 4 * hi;
            so[row * 64 + (t * 32 + lo)] = acc[t][reg];
        }
}

// -------------------------------- K3: exclusive scans (register-resident) ---
__global__ __launch_bounds__(256) void scan_skv(float* __restrict__ skv) {
    int id = blockIdx.x * 256 + threadIdx.x;   // H*R*D = 131072 columns
    int h = id >> 13, rd = id & 8191;
    float* p = skv + (size_t)h * NC * 8192 + rd;
    float vals[NC];
    #pragma unroll
    for (int n = 0; n < NC; ++n) vals[n] = p[(size_t)n * 8192];
    float run = 0.f;
    #pragma unroll
    for (int n = 0; n < NC; ++n) { float t = vals[n]; p[(size_t)n * 8192] = run; run += t; }
}

__global__ __launch_bounds__(256) void scan_zk(float* __restrict__ zk) {
    int id = blockIdx.x * 256 + threadIdx.x;   // H*R = 2048 columns
    int h = id >> 7, r = id & 127;
    float* p = zk + (size_t)h * NC * 128 + r;
    float vals[NC];
    #pragma unroll
    for (int n = 0; n < NC; ++n) vals[n] = p[n * 128];
    float run = 0.f;
    #pragma unroll
    for (int n = 0; n < NC; ++n) { float t = vals[n]; p[n * 128] = run; run += t; }
}

// ------------------- K4: fused A-GEMM + mask + den + num-GEMM + divide ------
// Per (h,chunk): A = mask(pq.pk^T) kept in LDS only; out = (A.v + pq.skv_prev)
// / (rowsum(A) + pq.zk_prev + eps). pq lives in registers (A-operand frags).
__global__ __launch_bounds__(256) void out_kernel(const unsigned short* __restrict__ pq,
                                                  const unsigned short* __restrict__ pk,
                                                  const float* __restrict__ v,
                                                  const float* __restrict__ skv,
                                                  const float* __restrict__ zk,
                                                  float* __restrict__ out) {
    __shared__ __align__(16) unsigned short pkl[128 * 128];  // pk, then masked A
    __shared__ __align__(16) unsigned short vl[128 * 64];
    __shared__ __align__(16) unsigned short skvl[128 * 64];
    __shared__ float zkl[128];
    __shared__ float denl[128];
    const int tid = threadIdx.x, hn = blockIdx.x;
    const int lane = tid & 63, wave = tid >> 6, lo = lane & 31, hi = lane >> 5;
    const int l0 = wave * 32;

    bf8 qf[8];                                             // pq strip in regs
    const unsigned short* pqg = pq + (size_t)hn * CHUNK * R;
    #pragma unroll
    for (int s = 0; s < 8; ++s)
        qf[s] = *(const bf8*)(pqg + (l0 + lo) * 128 + 16 * s + 8 * hi);

    const unsigned short* pkg = pk + (size_t)hn * CHUNK * R;
    for (int i = tid; i < 2048; i += 256) {
        int c = i >> 4, rb = (i & 15) * 8;
        *(bf8*)&pkl[(unsigned)((c * 128 + rb) ^ ((c & 7) << 3))] = *(const bf8*)(pkg + c * 128 + rb);
    }
    const float* vg = v + (size_t)hn * CHUNK * D;
    for (int i = tid; i < 2048; i += 256) {
        int c = i >> 4, d0 = (i & 15) * 4;
        float4 vv = *(const float4*)(vg + c * 64 + d0);
        unsigned* p = (unsigned*)&vl[(unsigned)((c * 64 + d0) ^ ((c & 7) << 3))];
        p[0] = (unsigned)f2b(vv.x) | ((unsigned)f2b(vv.y) << 16);
        p[1] = (unsigned)f2b(vv.z) | ((unsigned)f2b(vv.w) << 16);
    }
    const float* sg = skv + (size_t)hn * R * D;
    for (int i = tid; i < 2048; i += 256) {
        int r = i >> 4, d0 = (i & 15) * 4;
        float4 vv = *(const float4*)(sg + r * 64 + d0);
        unsigned* p = (unsigned*)&skvl[(unsigned)((r * 64 + d0) ^ ((r & 7) << 3))];
        p[0] = (unsigned)f2b(vv.x) | ((unsigned)f2b(vv.y) << 16);
        p[1] = (unsigned)f2b(vv.z) | ((unsigned)f2b(vv.w) << 16);
    }
    if (tid < 128) zkl[tid] = zk[(size_t)hn * 128 + tid];
    __syncthreads();

    // den_inter = dot(pq[row], zk_prev) from register frags
    float di = 0.f;
    #pragma unroll
    for (int s = 0; s < 8; ++s)
        #pragma unroll
        for (int e = 0; e < 8; ++e)
            di += b2f((unsigned short)qf[s][e]) * zkl[16 * s + 8 * hi + e];
    di += __shfl_xor(di, 32);

    // GEMM1: A = pq . pk^T (NT)
    facc16 acc1[4];
    #pragma unroll
    for (int t = 0; t < 4; ++t)
        #pragma unroll
        for (int e = 0; e < 16; ++e) acc1[t][e] = 0.f;
    #pragma unroll
    for (int s = 0; s < 8; ++s) {
        #pragma unroll
        for (int t = 0; t < 4; ++t) {
            const bf8 b = *(const bf8*)&pkl[(unsigned)(((t * 32 + lo) * 128 + 16 * s + 8 * hi) ^ (((t * 32 + lo) & 7) << 3))];
            acc1[t] = __builtin_amdgcn_mfma_f32_32x32x16_bf16(qf[s], b, acc1[t], 0, 0, 0);
        }
    }
    if (hi == 0) denl[l0 + lo] = di;
    __syncthreads();                       // all GEMM1 pk reads complete

    // masked A -> LDS (overwrites pk region)
    #pragma unroll
    for (int t = 0; t < 4; ++t)
        #pragma unroll
        for (int reg = 0; reg < 16; ++reg) {
            int row = l0 + (reg & 3) + 8 * (reg >> 2) + 4 * hi;
            int sc = t * 32 + lo;
            float val = (sc < row) ? acc1[t][reg] : 0.f;
            pkl[(unsigned)((row * 128 + sc) ^ ((row & 7) << 3))] = f2b(val);
        }
    __syncthreads();

    // den_intra: rowsum of masked A
    if (tid < 128) {
        float s2 = denl[tid];
        #pragma unroll
        for (int j = 0; j < 16; ++j) {
            bf8 a8 = *(const bf8*)&pkl[(unsigned)((tid * 128 + 8 * j) ^ ((tid & 7) << 3))];
            #pragma unroll
            for (int e = 0; e < 8; ++e) s2 += b2f((unsigned short)a8[e]);
        }
        denl[tid] = s2;
    }

    // GEMM2: num = A.v + pq.skv_prev
    facc16 acc2[2];
    #pragma unroll
    for (int t = 0; t < 2; ++t)
        #pragma unroll
        for (int e = 0; e < 16; ++e) acc2[t][e] = 0.f;
    #pragma unroll
    for (int s = 0; s < 8; ++s) {
        const bf8 a = *(const bf8*)&pkl[(unsigned)(((l0 + lo) * 128 + 16 * s + 8 * hi) ^ (((l0 + lo) & 7) << 3))];
        #pragma unroll
        for (int t = 0; t < 2; ++t) {
            bf8 b;
            #pragma unroll
            for (int e = 0; e < 8; ++e) {
                int k = 16 * s + 8 * hi + e;
                b[e] = (short)vl[(unsigned)((k * 64 + t * 32 + lo) ^ ((k & 7) << 3))];
            }
            acc2[t] = __builtin_amdgcn_mfma_f32_32x32x16_bf16(a, b, acc2[t], 0, 0, 0);
        }
    }
    #pragma unroll
    for (int s = 0; s < 8; ++s) {
        #pragma unroll
        for (int t = 0; t < 2; ++t) {
            bf8 b;
            #pragma unroll
            for (int e = 0; e < 8; ++e) {
                int k = 16 * s + 8 * hi + e;
                b[e] = (short)skvl[(unsigned)((k * 64 + t * 32 + lo) ^ ((k & 7) << 3))];
            }
            acc2[t] = __builtin_amdgcn_mfma_f32_32x32x16_bf16(qf[s], b, acc2[t], 0, 0, 0);
        }
    }
    __syncthreads();                        // denl complete

    float* og = out + (size_t)hn * CHUNK * D;
    #pragma unroll
    for (int t = 0; t < 2; ++t)
        #pragma unroll
        for (int reg = 0; reg < 16; ++reg) {
            int row = l0 + (reg & 3) + 8 * (reg >> 2) + 4 * hi;
            og[row * 64 + (t * 32 + lo)] = acc2[t][reg] / (denl[row] + EPS);
        }
}

// ---------------------------------------------------------------------------
extern "C" void kernel_launch(void* const* d_in, const int* in_sizes, int n_in,
                              void* d_out, int out_size, void* d_ws, size_t ws_size,
                              hipStream_t stream) {
    // setup_inputs order: {T, k, q, v, W}
    const float* k = (const float*)d_in[1];
    const float* q = (const float*)d_in[2];
    const float* v = (const float*)d_in[3];
    const float* W = (const float*)d_in[4];
    float* out = (float*)d_out;

    // ws: pq bf16 [HL*R] | pk bf16 [HL*R] | zk f32 [H*NC*R]   (~34 MB)
    unsigned short* pq = (unsigned short*)d_ws;
    unsigned short* pk = pq + (size_t)HL * R;
    float* zk = (float*)(pk + (size_t)HL * R);
    float* skv = out;   // skv chunks alias out chunks (staged to LDS before write)

    phi_kernel<<<HL / 128, 256, 0, stream>>>(q, W, pq);
    phi_kernel<<<HL / 128, 256, 0, stream>>>(k, W, pk);
    skv_kernel<<<H * NC, 256, 0, stream>>>(pk, v, skv, zk);
    scan_skv<<<(H * R * D) / 256, 256, 0, stream>>>(skv);
    scan_zk<<<(H * R) / 256, 256, 0, stream>>>(zk);
    out_kernel<<<H * NC, 256, 0, stream>>>(pq, pk, v, skv, zk, out);
}

// Round 3
// 60.207 us; speedup vs baseline: 3.6845x; 1.2633x over previous
//
#include <hip/hip_runtime.h>

#define H 16
#define L 4096
#define D 64
#define R 128
#define CHUNK 128
#define NC 32
#define HL (H * L)
#define HN (H * NC)
#define EPS 1e-10f
#define XS_SCALE 0.125f                    // sqrt(0.125)/64^0.25 == 1/8 exactly
#define PHI_SCALE 0.08838834764831845f     // 1/sqrt(128)

typedef __attribute__((ext_vector_type(8))) short bf8;     // 8 bf16 (4 VGPR)
typedef __attribute__((ext_vector_type(16))) float facc16; // 32x32 MFMA acc

__device__ __forceinline__ unsigned short f2b(float f) {
    unsigned u = __float_as_uint(f);
    return (unsigned short)((u + 0x7fffu + ((u >> 16) & 1u)) >> 16);  // RNE
}
__device__ __forceinline__ float b2f(unsigned short s) {
    return __uint_as_float(((unsigned)s) << 16);
}

// ---------------------------------------------------------------- K1: phi ---
// One launch covers q (blocks 0..511) and k (blocks 512..1023); 128 rows/blk.
__global__ __launch_bounds__(256) void phi_kernel(const float* __restrict__ q,
                                                  const float* __restrict__ k,
                                                  const float* __restrict__ W,
                                                  unsigned short* __restrict__ pq,
                                                  unsigned short* __restrict__ pk) {
    __shared__ __align__(16) unsigned short Wt[128 * 64];
    __shared__ __align__(16) unsigned short xs[128 * 64];
    __shared__ float sq[128];
    const int tid = threadIdx.x;
    const int isq = blockIdx.x < (HL / 128);
    const float* x = isq ? q : k;
    unsigned short* phi = isq ? pq : pk;
    const size_t row0 = (size_t)(isq ? blockIdx.x : blockIdx.x - HL / 128) * 128;

    for (int i = tid; i < 128 * 64; i += 256) {            // Wt[r][d] <- W[d][r]
        int r = i & 127, d = i >> 7;
        Wt[(unsigned)((r * 64 + d) ^ ((r & 7) << 3))] = f2b(W[d * 128 + r]);
    }
    for (int i = tid; i < 2048; i += 256) {                // xs + rowwise sq
        int row = i >> 4, d0 = (i & 15) * 4;
        const float4 vv = *(const float4*)(x + (row0 + row) * 64 + d0);
        float a0 = vv.x * XS_SCALE, a1 = vv.y * XS_SCALE;
        float a2 = vv.z * XS_SCALE, a3 = vv.w * XS_SCALE;
        float ss = a0 * a0 + a1 * a1 + a2 * a2 + a3 * a3;
        ss += __shfl_xor(ss, 1); ss += __shfl_xor(ss, 2);
        ss += __shfl_xor(ss, 4); ss += __shfl_xor(ss, 8);
        if ((tid & 15) == 0) sq[row] = 0.5f * ss;
        unsigned idx = (unsigned)((row * 64 + d0) ^ ((row & 7) << 3));
        unsigned* p = (unsigned*)&xs[idx];
        p[0] = (unsigned)f2b(a0) | ((unsigned)f2b(a1) << 16);
        p[1] = (unsigned)f2b(a2) | ((unsigned)f2b(a3) << 16);
    }
    __syncthreads();

    const int lane = tid & 63, wave = tid >> 6;
    const int lo = lane & 31, hi = lane >> 5;
    const int l0 = wave * 32;
    facc16 acc[4];
    #pragma unroll
    for (int t = 0; t < 4; ++t)
        #pragma unroll
        for (int e = 0; e < 16; ++e) acc[t][e] = 0.f;

    #pragma unroll
    for (int s = 0; s < 4; ++s) {                          // K = 64
        const bf8 a = *(const bf8*)&xs[(unsigned)(((l0 + lo) * 64 + 16 * s + 8 * hi) ^ ((lo & 7) << 3))];
        #pragma unroll
        for (int t = 0; t < 4; ++t) {
            const bf8 b = *(const bf8*)&Wt[(unsigned)(((t * 32 + lo) * 64 + 16 * s + 8 * hi) ^ ((lo & 7) << 3))];
            acc[t] = __builtin_amdgcn_mfma_f32_32x32x16_bf16(a, b, acc[t], 0, 0, 0);
        }
    }
    #pragma unroll
    for (int t = 0; t < 4; ++t)
        #pragma unroll
        for (int reg = 0; reg < 16; ++reg) {
            int row = l0 + (reg & 3) + 8 * (reg >> 2) + 4 * hi;
            int col = t * 32 + lo;
            float val = __expf(acc[t][reg] - sq[row]) * PHI_SCALE;
            phi[(row0 + row) * 128 + col] = f2b(val);
        }
}

// ------------------------------- K2: per-chunk skvT + zk + vT side-product --
// skvT[d][r] = sum_c vT[d][c] pk[c][r]; A=vT (LDS), B=pkT (LDS), all b128.
__global__ __launch_bounds__(256) void skv_kernel(const unsigned short* __restrict__ pk,
                                                  const float* __restrict__ v,
                                                  unsigned short* __restrict__ vT,
                                                  float* __restrict__ skvT,
                                                  float* __restrict__ zk) {
    __shared__ __align__(16) unsigned short pkT[128 * 128];  // [r][c] swz
    __shared__ __align__(16) unsigned short vTl[64 * 128];   // [d][c] swz
    const int tid = threadIdx.x, hn = blockIdx.x;
    const unsigned short* pkg = pk + (size_t)hn * CHUNK * R;
    const float* vg = v + (size_t)hn * CHUNK * D;

    for (int i = tid; i < 2048; i += 256) {                  // transpose pk -> pkT
        int c = i & 127, r0 = (i >> 7) * 8;
        bf8 t8 = *(const bf8*)(pkg + c * 128 + r0);
        #pragma unroll
        for (int e = 0; e < 8; ++e)
            pkT[(unsigned)(((r0 + e) * 128 + c) ^ (((r0 + e) & 7) << 3))] = (unsigned short)t8[e];
    }
    for (int i = tid; i < 8192; i += 256) {                  // transpose v -> vT bf16
        int d = i & 63, c = i >> 6;
        vTl[(unsigned)((d * 128 + c) ^ ((d & 7) << 3))] = f2b(vg[c * 64 + d]);
    }
    __syncthreads();

    unsigned short* vTg = vT + (size_t)hn * D * CHUNK;       // dump vT (linear)
    for (int i = tid; i < 1024; i += 256) {
        int d = i >> 4, c0 = (i & 15) * 8;
        *(bf8*)(vTg + d * 128 + c0) = *(const bf8*)&vTl[(unsigned)((d * 128 + c0) ^ ((d & 7) << 3))];
    }
    if (tid < 128) {                                         // zk[r] = rowsum pkT
        float s = 0.f;
        #pragma unroll
        for (int j = 0; j < 16; ++j) {
            bf8 a8 = *(const bf8*)&pkT[(unsigned)((tid * 128 + 8 * j) ^ ((tid & 7) << 3))];
            #pragma unroll
            for (int e = 0; e < 8; ++e) s += b2f((unsigned short)a8[e]);
        }
        zk[(size_t)hn * 128 + tid] = s;
    }

    const int lane = tid & 63, wave = tid >> 6, lo = lane & 31, hi = lane >> 5;
    facc16 acc[2];
    #pragma unroll
    for (int t = 0; t < 2; ++t)
        #pragma unroll
        for (int e = 0; e < 16; ++e) acc[t][e] = 0.f;
    #pragma unroll
    for (int s = 0; s < 8; ++s) {                            // K = 128 (c)
        const bf8 b = *(const bf8*)&pkT[(unsigned)(((wave * 32 + lo) * 128 + 16 * s + 8 * hi) ^ ((lo & 7) << 3))];
        #pragma unroll
        for (int db = 0; db < 2; ++db) {
            const bf8 a = *(const bf8*)&vTl[(unsigned)(((db * 32 + lo) * 128 + 16 * s + 8 * hi) ^ ((lo & 7) << 3))];
            acc[db] = __builtin_amdgcn_mfma_f32_32x32x16_bf16(a, b, acc[db], 0, 0, 0);
        }
    }
    float* sg = skvT + (size_t)hn * D * R;                   // [d][r] fp32
    #pragma unroll
    for (int db = 0; db < 2; ++db)
        #pragma unroll
        for (int reg = 0; reg < 16; ++reg) {
            int row = db * 32 + (reg & 3) + 8 * (reg >> 2) + 4 * hi;
            sg[row * 128 + wave * 32 + lo] = acc[db][reg];
        }
}

// ------------------- K3: exclusive scans over chunks (skvT + zk), bf16 out --
__global__ __launch_bounds__(256) void scan_kernel(const float* __restrict__ skvT,
                                                   unsigned short* __restrict__ skvTp,
                                                   const float* __restrict__ zk,
                                                   unsigned short* __restrict__ zkp) {
    const int bid = blockIdx.x;
    if (bid < 512) {
        int id = bid * 256 + threadIdx.x;                    // H*D*R = 131072 cols
        int h = id >> 13, dr = id & 8191;
        const float* p = skvT + (size_t)h * NC * 8192 + dr;
        unsigned short* o = skvTp + (size_t)h * NC * 8192 + dr;
        float run = 0.f;
        #pragma unroll
        for (int n = 0; n < NC; ++n) {
            float t = p[(size_t)n * 8192];
            o[(size_t)n * 8192] = f2b(run);
            run += t;
        }
    } else {
        int id = (bid - 512) * 256 + threadIdx.x;            // H*R = 2048 cols
        int h = id >> 7, r = id & 127;
        const float* p = zk + (size_t)h * NC * 128 + r;
        unsigned short* o = zkp + (size_t)h * NC * 128 + r;
        float run = 0.f;
        #pragma unroll
        for (int n = 0; n < NC; ++n) {
            float t = p[n * 128];
            o[n * 128] = f2b(run);
            run += t;
        }
    }
}

// ---- K4: fused A-GEMM + mask + num/den GEMM (den = 3rd MFMA tile) + divide -
__global__ __launch_bounds__(256) void out_kernel(const unsigned short* __restrict__ pq,
                                                  const unsigned short* __restrict__ pk,
                                                  const unsigned short* __restrict__ vT,
                                                  const unsigned short* __restrict__ skvTp,
                                                  const unsigned short* __restrict__ zkp,
                                                  float* __restrict__ out) {
    __shared__ __align__(16) unsigned short pkl[128 * 128];  // pk, then masked A
    __shared__ __align__(16) unsigned short vTl[64 * 128];   // [d][c]
    __shared__ __align__(16) unsigned short svl[64 * 128];   // [d][r]
    __shared__ __align__(16) unsigned short dB1[32 * 128];   // row0 = ones (k=c)
    __shared__ __align__(16) unsigned short dB2[32 * 128];   // row0 = zk_prev (k=r)
    const int tid = threadIdx.x, hn = blockIdx.x;
    const int lane = tid & 63, wave = tid >> 6, lo = lane & 31, hi = lane >> 5;
    const int l0 = wave * 32;

    bf8 qf[8];                                               // pq strip in regs
    const unsigned short* pqg = pq + (size_t)hn * CHUNK * R;
    #pragma unroll
    for (int s = 0; s < 8; ++s)
        qf[s] = *(const bf8*)(pqg + (l0 + lo) * 128 + 16 * s + 8 * hi);

    const unsigned short* pkg = pk + (size_t)hn * CHUNK * R;
    for (int i = tid; i < 2048; i += 256) {
        int c = i >> 4, rb = (i & 15) * 8;
        *(bf8*)&pkl[(unsigned)((c * 128 + rb) ^ ((c & 7) << 3))] = *(const bf8*)(pkg + c * 128 + rb);
    }
    const unsigned short* vTg = vT + (size_t)hn * D * CHUNK;
    const unsigned short* svg = skvTp + (size_t)hn * D * R;
    for (int i = tid; i < 1024; i += 256) {
        int d = i >> 4, c0 = (i & 15) * 8;
        unsigned idx = (unsigned)((d * 128 + c0) ^ ((d & 7) << 3));
        *(bf8*)&vTl[idx] = *(const bf8*)(vTg + d * 128 + c0);
        *(bf8*)&svl[idx] = *(const bf8*)(svg + d * 128 + c0);
    }
    if (tid < 128) {
        dB1[tid] = 0x3F80;                                   // 1.0 bf16
        dB2[tid] = zkp[(size_t)hn * 128 + tid];
    }
    __syncthreads();

    // GEMM1: A = pq . pk^T  (cols = chunk pos s, K = r)
    facc16 acc1[4];
    #pragma unroll
    for (int t = 0; t < 4; ++t)
        #pragma unroll
        for (int e = 0; e < 16; ++e) acc1[t][e] = 0.f;
    #pragma unroll
    for (int s = 0; s < 8; ++s)
        #pragma unroll
        for (int t = 0; t < 4; ++t) {
            const bf8 b = *(const bf8*)&pkl[(unsigned)(((t * 32 + lo) * 128 + 16 * s + 8 * hi) ^ ((lo & 7) << 3))];
            acc1[t] = __builtin_amdgcn_mfma_f32_32x32x16_bf16(qf[s], b, acc1[t], 0, 0, 0);
        }
    __syncthreads();                                         // GEMM1 pk reads done

    #pragma unroll
    for (int t = 0; t < 4; ++t)                              // masked A -> LDS
        #pragma unroll
        for (int reg = 0; reg < 16; ++reg) {
            int row = l0 + (reg & 3) + 8 * (reg >> 2) + 4 * hi;
            int sc = t * 32 + lo;
            pkl[(unsigned)((row * 128 + sc) ^ ((row & 7) << 3))] = f2b(sc < row ? acc1[t][reg] : 0.f);
        }
    __syncthreads();

    // GEMM2: cols 0..63 = num (d), cols 64..95 = den (only col 64 real)
    facc16 acc2[3];
    #pragma unroll
    for (int t = 0; t < 3; ++t)
        #pragma unroll
        for (int e = 0; e < 16; ++e) acc2[t][e] = 0.f;
    #pragma unroll
    for (int s = 0; s < 8; ++s) {                            // pass A: k = c
        const bf8 a = *(const bf8*)&pkl[(unsigned)(((l0 + lo) * 128 + 16 * s + 8 * hi) ^ ((lo & 7) << 3))];
        #pragma unroll
        for (int t = 0; t < 2; ++t) {
            const bf8 b = *(const bf8*)&vTl[(unsigned)(((t * 32 + lo) * 128 + 16 * s + 8 * hi) ^ ((lo & 7) << 3))];
            acc2[t] = __builtin_amdgcn_mfma_f32_32x32x16_bf16(a, b, acc2[t], 0, 0, 0);
        }
        const bf8 bd = *(const bf8*)&dB1[(unsigned)((lo * 128 + 16 * s + 8 * hi) ^ ((lo & 7) << 3))];
        acc2[2] = __builtin_amdgcn_mfma_f32_32x32x16_bf16(a, bd, acc2[2], 0, 0, 0);
    }
    #pragma unroll
    for (int s = 0; s < 8; ++s) {                            // pass B: k = r
        #pragma unroll
        for (int t = 0; t < 2; ++t) {
            const bf8 b = *(const bf8*)&svl[(unsigned)(((t * 32 + lo) * 128 + 16 * s + 8 * hi) ^ ((lo & 7) << 3))];
            acc2[t] = __builtin_amdgcn_mfma_f32_32x32x16_bf16(qf[s], b, acc2[t], 0, 0, 0);
        }
        const bf8 bd = *(const bf8*)&dB2[(unsigned)((lo * 128 + 16 * s + 8 * hi) ^ ((lo & 7) << 3))];
        acc2[2] = __builtin_amdgcn_mfma_f32_32x32x16_bf16(qf[s], bd, acc2[2], 0, 0, 0);
    }

    float* og = out + (size_t)hn * CHUNK * D;
    #pragma unroll
    for (int reg = 0; reg < 16; ++reg) {
        int row = l0 + (reg & 3) + 8 * (reg >> 2) + 4 * hi;
        float dv = __shfl(acc2[2][reg], lane & 32);          // col 64 holder: lo==0
        float inv = 1.0f / (dv + EPS);
        og[row * 64 + lo]      = acc2[0][reg] * inv;
        og[row * 64 + 32 + lo] = acc2[1][reg] * inv;
    }
}

// ---------------------------------------------------------------------------
extern "C" void kernel_launch(void* const* d_in, const int* in_sizes, int n_in,
                              void* d_out, int out_size, void* d_ws, size_t ws_size,
                              hipStream_t stream) {
    // setup_inputs order: {T, k, q, v, W}
    const float* k = (const float*)d_in[1];
    const float* q = (const float*)d_in[2];
    const float* v = (const float*)d_in[3];
    const float* W = (const float*)d_in[4];

    // ws (u16 units): pq | pk | vT | skvTp | zk(f32) | zkp   (~48.4 MB)
    unsigned short* pq = (unsigned short*)d_ws;
    unsigned short* pk = pq + (size_t)HL * R;
    unsigned short* vT = pk + (size_t)HL * R;
    unsigned short* skvTp = vT + (size_t)HN * D * CHUNK;
    float* zk = (float*)(skvTp + (size_t)HN * D * R);
    unsigned short* zkp = (unsigned short*)(zk + (size_t)HN * R);
    float* skvT = (float*)d_out;   // fp32 chunk summaries alias d_out (scan consumes
                                   // them before out_kernel overwrites d_out)

    phi_kernel<<<2 * (HL / 128), 256, 0, stream>>>(q, k, W, pq, pk);
    skv_kernel<<<HN, 256, 0, stream>>>(pk, v, vT, skvT, zk);
    scan_kernel<<<520, 256, 0, stream>>>(skvT, skvTp, zk, zkp);
    out_kernel<<<HN, 256, 0, stream>>>(pq, pk, vT, skvTp, zkp, (float*)d_out);
}

// Round 5
// 54.896 us; speedup vs baseline: 4.0410x; 1.0967x over previous
//
#include <hip/hip_runtime.h>
#include <hip/hip_cooperative_groups.h>

namespace cg = cooperative_groups;

#define H 16
#define L 4096
#define D 64
#define R 128
#define CHUNK 128
#define NC 32
#define HL (H * L)
#define HN (H * NC)
#define EPS 1e-10f
#define XS_SCALE 0.125f                    // sqrt(0.125)/64^0.25 == 1/8 exactly
#define PHI_SCALE 0.08838834764831845f     // 1/sqrt(128)

typedef __attribute__((ext_vector_type(8))) short bf8;     // 8 bf16
typedef __attribute__((ext_vector_type(4))) short bf4;     // 4 bf16
typedef __attribute__((ext_vector_type(16))) float facc16; // 32x32 MFMA acc

__device__ __forceinline__ unsigned short f2b(float f) {
    unsigned u = __float_as_uint(f);
    return (unsigned short)((u + 0x7fffu + ((u >> 16) & 1u)) >> 16);  // RNE
}
__device__ __forceinline__ float b2f(unsigned short s) {
    return __uint_as_float(((unsigned)s) << 16);
}

// ============ PHASE 1: phi_q (->qf regs + bufA), phi_k (->bufA pk + bufC pkT),
//              vT (->bufB), skvT f32 -> stage, zk. Optional global dumps. =====
template<bool DUMP>
__device__ __forceinline__ void phase1(
    const float* __restrict__ q, const float* __restrict__ k,
    const float* __restrict__ v, const float* __restrict__ W,
    unsigned short* bufA, unsigned short* bufB, unsigned short* bufC,
    float* __restrict__ stage, float* __restrict__ zk,
    unsigned short* __restrict__ pqd, unsigned short* __restrict__ pkd,
    unsigned short* __restrict__ vTd, bf8* qf, int hn, int tid)
{
    unsigned short* Wt = bufC;              // [r][d] 128x64
    unsigned short* xs = bufC + 8192;       // [row][d] 128x64
    float* sq = (float*)bufB;               // 128 f32 during phi
    const int lane = tid & 63, wave = tid >> 6, lo = lane & 31, hi = lane >> 5;
    const int l0 = wave * 32;
    const size_t cbase = (size_t)hn * CHUNK * D;

    for (int i = tid; i < 8192; i += 256) {                 // Wt[r][d] <- W[d][r]
        int r = i & 127, d = i >> 7;
        Wt[(unsigned)((r * 64 + d) ^ ((r & 7) << 3))] = f2b(W[d * 128 + r]);
    }
    for (int i = tid; i < 2048; i += 256) {                 // xs_q + sq_q
        int row = i >> 4, d0 = (i & 15) * 4;
        float4 vv = *(const float4*)(q + cbase + row * 64 + d0);
        float a0 = vv.x * XS_SCALE, a1 = vv.y * XS_SCALE;
        float a2 = vv.z * XS_SCALE, a3 = vv.w * XS_SCALE;
        float ss = a0 * a0 + a1 * a1 + a2 * a2 + a3 * a3;
        ss += __shfl_xor(ss, 1); ss += __shfl_xor(ss, 2);
        ss += __shfl_xor(ss, 4); ss += __shfl_xor(ss, 8);
        if ((tid & 15) == 0) sq[row] = 0.5f * ss;
        unsigned idx = (unsigned)((row * 64 + d0) ^ ((row & 7) << 3));
        unsigned* p = (unsigned*)&xs[idx];
        p[0] = (unsigned)f2b(a0) | ((unsigned)f2b(a1) << 16);
        p[1] = (unsigned)f2b(a2) | ((unsigned)f2b(a3) << 16);
    }
    __syncthreads();

    {   // phi_q -> bufA pq[c][r]
        facc16 acc[4];
        #pragma unroll
        for (int t = 0; t < 4; ++t)
            #pragma unroll
            for (int e = 0; e < 16; ++e) acc[t][e] = 0.f;
        #pragma unroll
        for (int s = 0; s < 4; ++s) {
            const bf8 a = *(const bf8*)&xs[(unsigned)(((l0 + lo) * 64 + 16 * s + 8 * hi) ^ ((lo & 7) << 3))];
            #pragma unroll
            for (int t = 0; t < 4; ++t) {
                const bf8 b = *(const bf8*)&Wt[(unsigned)(((t * 32 + lo) * 64 + 16 * s + 8 * hi) ^ ((lo & 7) << 3))];
                acc[t] = __builtin_amdgcn_mfma_f32_32x32x16_bf16(a, b, acc[t], 0, 0, 0);
            }
        }
        #pragma unroll
        for (int t = 0; t < 4; ++t)
            #pragma unroll
            for (int reg = 0; reg < 16; ++reg) {
                int row = l0 + (reg & 3) + 8 * (reg >> 2) + 4 * hi;
                int col = t * 32 + lo;
                bufA[(unsigned)((row * 128 + col) ^ ((row & 7) << 3))] =
                    f2b(__expf(acc[t][reg] - sq[row]) * PHI_SCALE);
            }
    }
    __syncthreads();

    #pragma unroll
    for (int s = 0; s < 8; ++s)                             // pq strip -> regs
        qf[s] = *(const bf8*)&bufA[(unsigned)(((l0 + lo) * 128 + 16 * s + 8 * hi) ^ ((lo & 7) << 3))];
    if constexpr (DUMP) {
        unsigned short* pg = pqd + (size_t)hn * CHUNK * R;
        for (int i = tid; i < 2048; i += 256) {
            int c = i >> 4, rb = (i & 15) * 8;
            *(bf8*)(pg + c * 128 + rb) = *(const bf8*)&bufA[(unsigned)((c * 128 + rb) ^ ((c & 7) << 3))];
        }
    }

    for (int i = tid; i < 2048; i += 256) {                 // xs_k + sq_k
        int row = i >> 4, d0 = (i & 15) * 4;
        float4 vv = *(const float4*)(k + cbase + row * 64 + d0);
        float a0 = vv.x * XS_SCALE, a1 = vv.y * XS_SCALE;
        float a2 = vv.z * XS_SCALE, a3 = vv.w * XS_SCALE;
        float ss = a0 * a0 + a1 * a1 + a2 * a2 + a3 * a3;
        ss += __shfl_xor(ss, 1); ss += __shfl_xor(ss, 2);
        ss += __shfl_xor(ss, 4); ss += __shfl_xor(ss, 8);
        if ((tid & 15) == 0) sq[row] = 0.5f * ss;
        unsigned idx = (unsigned)((row * 64 + d0) ^ ((row & 7) << 3));
        unsigned* p = (unsigned*)&xs[idx];
        p[0] = (unsigned)f2b(a0) | ((unsigned)f2b(a1) << 16);
        p[1] = (unsigned)f2b(a2) | ((unsigned)f2b(a3) << 16);
    }
    __syncthreads();                                        // xs_k ready; bufA reads done

    facc16 acck[4];
    #pragma unroll
    for (int t = 0; t < 4; ++t)
        #pragma unroll
        for (int e = 0; e < 16; ++e) acck[t][e] = 0.f;
    #pragma unroll
    for (int s = 0; s < 4; ++s) {
        const bf8 a = *(const bf8*)&xs[(unsigned)(((l0 + lo) * 64 + 16 * s + 8 * hi) ^ ((lo & 7) << 3))];
        #pragma unroll
        for (int t = 0; t < 4; ++t) {
            const bf8 b = *(const bf8*)&Wt[(unsigned)(((t * 32 + lo) * 64 + 16 * s + 8 * hi) ^ ((lo & 7) << 3))];
            acck[t] = __builtin_amdgcn_mfma_f32_32x32x16_bf16(a, b, acck[t], 0, 0, 0);
        }
    }
    __syncthreads();                                        // Wt/xs reads done -> bufC free

    #pragma unroll
    for (int t = 0; t < 4; ++t) {                           // phi_k -> pk(bufA) + pkT(bufC)
        int colr = t * 32 + lo;
        #pragma unroll
        for (int g = 0; g < 4; ++g) {
            int c0 = l0 + 8 * g + 4 * hi;
            bf4 pk4;
            #pragma unroll
            for (int e = 0; e < 4; ++e) {
                unsigned short b = f2b(__expf(acck[t][4 * g + e] - sq[c0 + e]) * PHI_SCALE);
                pk4[e] = (short)b;
                bufA[(unsigned)(((c0 + e) * 128 + colr) ^ (((c0 + e) & 7) << 3))] = b;
            }
            *(bf4*)&bufC[(unsigned)((colr * 128 + c0) ^ ((colr & 7) << 3))] = pk4;
        }
    }
    __syncthreads();                                        // sq dead; pkT/pk ready

    for (int i = tid; i < 8192; i += 256) {                 // vT[d][c] <- v (bf16)
        int d = i & 63, c = i >> 6;
        bufB[(unsigned)((d * 128 + c) ^ ((d & 7) << 3))] = f2b(v[cbase + c * 64 + d]);
    }
    if (tid < 128) {                                        // zk[r] = rowsum pkT
        float s = 0.f;
        #pragma unroll
        for (int j = 0; j < 16; ++j) {
            bf8 a8 = *(const bf8*)&bufC[(unsigned)((tid * 128 + 8 * j) ^ ((tid & 7) << 3))];
            #pragma unroll
            for (int e = 0; e < 8; ++e) s += b2f((unsigned short)a8[e]);
        }
        zk[(size_t)hn * 128 + tid] = s;
    }
    if constexpr (DUMP) {
        unsigned short* pg = pkd + (size_t)hn * CHUNK * R;
        for (int i = tid; i < 2048; i += 256) {
            int c = i >> 4, rb = (i & 15) * 8;
            *(bf8*)(pg + c * 128 + rb) = *(const bf8*)&bufA[(unsigned)((c * 128 + rb) ^ ((c & 7) << 3))];
        }
    }
    __syncthreads();

    if constexpr (DUMP) {
        unsigned short* vg2 = vTd + (size_t)hn * D * CHUNK;
        for (int i = tid; i < 1024; i += 256) {
            int d = i >> 4, c0 = (i & 15) * 8;
            *(bf8*)(vg2 + d * 128 + c0) = *(const bf8*)&bufB[(unsigned)((d * 128 + c0) ^ ((d & 7) << 3))];
        }
    }
    {   // skvT[d][r] = sum_c vT[d][c] pkT[r][c]  -> stage (f32)
        facc16 accs[2];
        #pragma unroll
        for (int t = 0; t < 2; ++t)
            #pragma unroll
            for (int e = 0; e < 16; ++e) accs[t][e] = 0.f;
        #pragma unroll
        for (int s = 0; s < 8; ++s) {
            const bf8 b = *(const bf8*)&bufC[(unsigned)(((wave * 32 + lo) * 128 + 16 * s + 8 * hi) ^ ((lo & 7) << 3))];
            #pragma unroll
            for (int db = 0; db < 2; ++db) {
                const bf8 a = *(const bf8*)&bufB[(unsigned)(((db * 32 + lo) * 128 + 16 * s + 8 * hi) ^ ((lo & 7) << 3))];
                accs[db] = __builtin_amdgcn_mfma_f32_32x32x16_bf16(a, b, accs[db], 0, 0, 0);
            }
        }
        float* sg = stage + (size_t)hn * D * R;
        #pragma unroll
        for (int db = 0; db < 2; ++db)
            #pragma unroll
            for (int reg = 0; reg < 16; ++reg) {
                int row = db * 32 + (reg & 3) + 8 * (reg >> 2) + 4 * hi;
                sg[row * 128 + wave * 32 + lo] = accs[db][reg];
            }
    }
}

// ============ PHASE 2: exclusive prefix over chunks (skvT + zk) =============
__device__ __forceinline__ void phase2(const float* __restrict__ stage,
                                       unsigned short* __restrict__ skvTp,
                                       const float* __restrict__ zk,
                                       unsigned short* __restrict__ zkp,
                                       int bid, int tid)
{
    int g = bid * 256 + tid;                                // 131072 = H*D*R
    int h2 = g >> 13, dr = g & 8191;
    const float* p = stage + (size_t)h2 * NC * 8192 + dr;
    unsigned short* o = skvTp + (size_t)h2 * NC * 8192 + dr;
    float run = 0.f;
    #pragma unroll
    for (int n = 0; n < NC; ++n) {
        float t = p[(size_t)n * 8192];
        o[(size_t)n * 8192] = f2b(run);
        run += t;
    }
    if (g < 2048) {                                         // H*R zk columns
        int h3 = g >> 7, r = g & 127;
        const float* pz = zk + (size_t)h3 * NC * 128 + r;
        unsigned short* oz = zkp + (size_t)h3 * NC * 128 + r;
        float runz = 0.f;
        #pragma unroll
        for (int n = 0; n < NC; ++n) {
            float t2 = pz[n * 128];
            oz[n * 128] = f2b(runz);
            runz += t2;
        }
    }
}

// ============ PHASE 3: A-GEMM + mask + num/den GEMM + divide ================
// Requires pk in bufA, vT in bufB, qf in regs. Stages svl into bufC itself.
__device__ __forceinline__ void phase3(
    unsigned short* bufA, unsigned short* bufB, unsigned short* bufC,
    const unsigned short* __restrict__ skvTp, const unsigned short* __restrict__ zkp,
    const bf8* qf, int hn, int tid, float* __restrict__ out)
{
    const int lane = tid & 63, wave = tid >> 6, lo = lane & 31, hi = lane >> 5;
    const int l0 = wave * 32;
    __syncthreads();                                        // caller staging visible

    const unsigned short* svg = skvTp + (size_t)hn * D * R;
    for (int i = tid; i < 1024; i += 256) {
        int d = i >> 4, r0 = (i & 15) * 8;
        *(bf8*)&bufC[(unsigned)((d * 128 + r0) ^ ((d & 7) << 3))] = *(const bf8*)(svg + d * 128 + r0);
    }
    bf8 zf[8], onesf;
    #pragma unroll
    for (int e = 0; e < 8; ++e) onesf[e] = (lo == 0) ? (short)0x3F80 : (short)0;
    #pragma unroll
    for (int s = 0; s < 8; ++s)
        #pragma unroll
        for (int e = 0; e < 8; ++e) zf[s][e] = 0;
    if (lo == 0) {
        #pragma unroll
        for (int s = 0; s < 8; ++s)
            zf[s] = *(const bf8*)(zkp + (size_t)hn * 128 + 16 * s + 8 * hi);
    }

    facc16 acc1[4];                                         // GEMM1: A = pq.pk^T
    #pragma unroll
    for (int t = 0; t < 4; ++t)
        #pragma unroll
        for (int e = 0; e < 16; ++e) acc1[t][e] = 0.f;
    #pragma unroll
    for (int s = 0; s < 8; ++s)
        #pragma unroll
        for (int t = 0; t < 4; ++t) {
            const bf8 b = *(const bf8*)&bufA[(unsigned)(((t * 32 + lo) * 128 + 16 * s + 8 * hi) ^ ((lo & 7) << 3))];
            acc1[t] = __builtin_amdgcn_mfma_f32_32x32x16_bf16(qf[s], b, acc1[t], 0, 0, 0);
        }
    __syncthreads();                                        // pk reads + svl staging done

    #pragma unroll
    for (int t = 0; t < 4; ++t)                             // masked A -> bufA
        #pragma unroll
        for (int reg = 0; reg < 16; ++reg) {
            int row = l0 + (reg & 3) + 8 * (reg >> 2) + 4 * hi;
            int sc = t * 32 + lo;
            bufA[(unsigned)((row * 128 + sc) ^ ((row & 7) << 3))] = f2b(sc < row ? acc1[t][reg] : 0.f);
        }
    __syncthreads();

    facc16 acc2[3];                                         // num d0-31, d32-63, den
    #pragma unroll
    for (int t = 0; t < 3; ++t)
        #pragma unroll
        for (int e = 0; e < 16; ++e) acc2[t][e] = 0.f;
    #pragma unroll
    for (int s = 0; s < 8; ++s) {                           // pass A: k = c
        const bf8 a = *(const bf8*)&bufA[(unsigned)(((l0 + lo) * 128 + 16 * s + 8 * hi) ^ ((lo & 7) << 3))];
        #pragma unroll
        for (int t = 0; t < 2; ++t) {
            const bf8 b = *(const bf8*)&bufB[(unsigned)(((t * 32 + lo) * 128 + 16 * s + 8 * hi) ^ ((lo & 7) << 3))];
            acc2[t] = __builtin_amdgcn_mfma_f32_32x32x16_bf16(a, b, acc2[t], 0, 0, 0);
        }
        acc2[2] = __builtin_amdgcn_mfma_f32_32x32x16_bf16(a, onesf, acc2[2], 0, 0, 0);
    }
    #pragma unroll
    for (int s = 0; s < 8; ++s) {                           // pass B: k = r
        #pragma unroll
        for (int t = 0; t < 2; ++t) {
            const bf8 b = *(const bf8*)&bufC[(unsigned)(((t * 32 + lo) * 128 + 16 * s + 8 * hi) ^ ((lo & 7) << 3))];
            acc2[t] = __builtin_amdgcn_mfma_f32_32x32x16_bf16(qf[s], b, acc2[t], 0, 0, 0);
        }
        acc2[2] = __builtin_amdgcn_mfma_f32_32x32x16_bf16(qf[s], zf[s], acc2[2], 0, 0, 0);
    }

    float* og = out + (size_t)hn * CHUNK * D;
    #pragma unroll
    for (int reg = 0; reg < 16; ++reg) {
        int row = l0 + (reg & 3) + 8 * (reg >> 2) + 4 * hi;
        float dv = __shfl(acc2[2][reg], lane & 32);         // den col lives at lo==0
        float inv = 1.0f / (dv + EPS);
        og[row * 64 + lo]      = acc2[0][reg] * inv;
        og[row * 64 + 32 + lo] = acc2[1][reg] * inv;
    }
}

// ============================ kernels =======================================
__global__ __launch_bounds__(256, 2) void fused_coop(
    const float* __restrict__ q, const float* __restrict__ k,
    const float* __restrict__ v, const float* __restrict__ W,
    unsigned short* __restrict__ skvTp, unsigned short* __restrict__ zkp,
    float* __restrict__ zk, float* __restrict__ out)
{
    __shared__ __align__(16) unsigned short LDSm[40960];    // 80 KB
    unsigned short* bufA = LDSm;
    unsigned short* bufB = LDSm + 16384;
    unsigned short* bufC = LDSm + 24576;
    const int tid = threadIdx.x, hn = blockIdx.x;
    bf8 qf[8];
    phase1<false>(q, k, v, W, bufA, bufB, bufC, out, zk,
                  nullptr, nullptr, nullptr, qf, hn, tid);
    __threadfence();
    cg::this_grid().sync();
    phase2(out, skvTp, zk, zkp, hn, tid);
    __threadfence();
    cg::this_grid().sync();
    __threadfence();
    phase3(bufA, bufB, bufC, skvTp, zkp, qf, hn, tid, out);
}

__global__ __launch_bounds__(256, 2) void kA(
    const float* __restrict__ q, const float* __restrict__ k,
    const float* __restrict__ v, const float* __restrict__ W,
    float* __restrict__ stage, float* __restrict__ zk,
    unsigned short* __restrict__ pqd, unsigned short* __restrict__ pkd,
    unsigned short* __restrict__ vTd)
{
    __shared__ __align__(16) unsigned short LDSm[40960];
    bf8 qf[8];
    phase1<true>(q, k, v, W, LDSm, LDSm + 16384, LDSm + 24576, stage, zk,
                 pqd, pkd, vTd, qf, blockIdx.x, threadIdx.x);
}

__global__ __launch_bounds__(256) void kB(const float* __restrict__ stage,
                                          unsigned short* __restrict__ skvTp,
                                          const float* __restrict__ zk,
                                          unsigned short* __restrict__ zkp)
{
    phase2(stage, skvTp, zk, zkp, blockIdx.x, threadIdx.x);
}

__global__ __launch_bounds__(256, 2) void kC(
    const unsigned short* __restrict__ pq, const unsigned short* __restrict__ pk,
    const unsigned short* __restrict__ vT, const unsigned short* __restrict__ skvTp,
    const unsigned short* __restrict__ zkp, float* __restrict__ out)
{
    __shared__ __align__(16) unsigned short LDSm[32768];    // 64 KB
    unsigned short* bufA = LDSm;                            // pk 32KB
    unsigned short* bufB = LDSm + 16384;                    // vT 16KB
    unsigned short* bufC = LDSm + 24576;                    // svl 16KB
    const int tid = threadIdx.x, hn = blockIdx.x;
    const int lane = tid & 63, wave = tid >> 6, lo = lane & 31, hi = lane >> 5;
    const int l0 = wave * 32;

    bf8 qf[8];
    const unsigned short* pqg = pq + (size_t)hn * CHUNK * R;
    #pragma unroll
    for (int s = 0; s < 8; ++s)
        qf[s] = *(const bf8*)(pqg + (l0 + lo) * 128 + 16 * s + 8 * hi);

    const unsigned short* pkg = pk + (size_t)hn * CHUNK * R;
    for (int i = tid; i < 2048; i += 256) {
        int c = i >> 4, rb = (i & 15) * 8;
        *(bf8*)&bufA[(unsigned)((c * 128 + rb) ^ ((c & 7) << 3))] = *(const bf8*)(pkg + c * 128 + rb);
    }
    const unsigned short* vTg = vT + (size_t)hn * D * CHUNK;
    for (int i = tid; i < 1024; i += 256) {
        int d = i >> 4, c0 = (i & 15) * 8;
        *(bf8*)&bufB[(unsigned)((d * 128 + c0) ^ ((d & 7) << 3))] = *(const bf8*)(vTg + d * 128 + c0);
    }
    phase3(bufA, bufB, bufC, skvTp, zkp, qf, hn, tid, out);  // starts with syncthreads
}

// ---------------------------------------------------------------------------
extern "C" void kernel_launch(void* const* d_in, const int* in_sizes, int n_in,
                              void* d_out, int out_size, void* d_ws, size_t ws_size,
                              hipStream_t stream) {
    // setup_inputs order: {T, k, q, v, W}
    const float* k = (const float*)d_in[1];
    const float* q = (const float*)d_in[2];
    const float* v = (const float*)d_in[3];
    const float* W = (const float*)d_in[4];
    float* out = (float*)d_out;

    // ws: skvTp u16 | zkp u16 | zk f32 | pq u16 | pk u16 | vT u16  (~49 MB)
    unsigned short* skvTp = (unsigned short*)d_ws;
    unsigned short* zkp = skvTp + (size_t)HN * D * R;
    float* zk = (float*)(zkp + (size_t)HN * R);
    unsigned short* pq = (unsigned short*)(zk + (size_t)HN * R);
    unsigned short* pk = pq + (size_t)HL * R;
    unsigned short* vT = pk + (size_t)HL * R;

    int nb = 0;
    hipError_t qrc = hipOccupancyMaxActiveBlocksPerMultiprocessor(
        &nb, (const void*)fused_coop, 256, 0);
    bool launched = false;
    if (qrc == hipSuccess && nb >= 2) {
        void* kargs[8] = {(void*)&q, (void*)&k, (void*)&v, (void*)&W,
                          (void*)&skvTp, (void*)&zkp, (void*)&zk, (void*)&out};
        hipError_t rc = hipLaunchCooperativeKernel((const void*)fused_coop,
                                                   dim3(HN), dim3(256), kargs, 0, stream);
        launched = (rc == hipSuccess);
        if (!launched) (void)hipGetLastError();             // clear sticky error
    }
    if (!launched) {
        kA<<<HN, 256, 0, stream>>>(q, k, v, W, out, zk, pq, pk, vT);
        kB<<<HN, 256, 0, stream>>>(out, skvTp, zk, zkp);
        kC<<<HN, 256, 0, stream>>>(pq, pk, vT, skvTp, zkp, out);
    }
}